// Round 1
// 413.911 us; speedup vs baseline: 1.0487x; 1.0487x over previous
//
#include <hip/hip_runtime.h>
#include <cstdint>

// SiVALinear factorized path, R5:
//  - Port BOTH GEMMs from the 128^2 2-barrier structure (~708 TF measured, MfmaUtil 30%,
//    8.4M LDS bank conflicts, vmcnt(0)+full drain per K-step) to the 256^2 8-phase
//    counted-vmcnt template (T1 XCD swizzle + T2 LDS XOR swizzle + T3/T4 counted vmcnt(4)
//    + T5 setprio). 8 waves (2Mx4N), BK=64 split as two 32-wide k-half-tiles, 128 KiB LDS
//    double buffer, ONE vmcnt(4) per K-tile (never 0 in steady state), raw s_barrier
//    (NOT __syncthreads -> avoids the compiler's vmcnt(0) drain).
//  - LDS swizzle: 16B chunk (row,cc) stored at cc^((row>>1)&3); applied on BOTH sides
//    (pre-swizzled global source feeding linear global_load_lds dest + swizzled ds_read).
//    Fragment reads then hit all 32 banks at 2-way (free).
//  - gemm_a keeps split-K=2 (256 blocks = 1/CU; 256^2 tiles without split would leave
//    half the CUs idle) + existing verified reduce_y. gemm_b: 512 blocks.
//  - Hazard schedule (per K-tile t, buf bb=t&1): p0 reads A(bb,k0)+B(bb,k0), issues
//    A(bb^1,k1,t+1); p1 reads A(bb,k0,mh1), issues B(bb^1,k1,t+1); p2 reads A(bb,k1)+
//    B(bb,k1), issues A(bb,k0,t+2); p3 reads A(bb,k1,mh1), issues B(bb,k0,t+2), waits
//    vmcnt(4). Every slot overwrite is issued >=1 barrier after its last reader.

typedef __bf16 bf16x8 __attribute__((ext_vector_type(8)));
typedef float f32x4 __attribute__((ext_vector_type(4)));

__device__ __forceinline__ unsigned short f32_to_bf16(float f) {
    union { float f; uint32_t u; } v; v.f = f;
    uint32_t u = v.u;
    u += 0x7FFF + ((u >> 16) & 1);   // RNE
    return (unsigned short)(u >> 16);
}

// ---------- cast fp32 -> bf16, vec4 ----------
__global__ void cast_f32_bf16(const float* __restrict__ src,
                              unsigned short* __restrict__ dst, int n4) {
    int i = blockIdx.x * blockDim.x + threadIdx.x;
    if (i >= n4) return;
    float4 v = ((const float4*)src)[i];
    ushort4 o;
    o.x = f32_to_bf16(v.x); o.y = f32_to_bf16(v.y);
    o.z = f32_to_bf16(v.z); o.w = f32_to_bf16(v.w);
    ((ushort4*)dst)[i] = o;
}

// ---------- build U_cat[o, r] * S[r] -> bf16 [4096 x 1024] row-major ----------
__global__ void build_u(const float* __restrict__ u_t, const float* __restrict__ u_d,
                        const float* __restrict__ s, unsigned short* __restrict__ ub,
                        int n4) {
    int i = blockIdx.x * blockDim.x + threadIdx.x;
    if (i >= n4) return;
    int e = i * 4;
    int o = e >> 10;
    int r = e & 1023;
    float4 u;
    if (r < 64) u = *(const float4*)(u_t + (size_t)o * 64 + r);
    else        u = *(const float4*)(u_d + (size_t)o * 960 + (r - 64));
    float4 sv = *(const float4*)(s + r);
    ushort4 w;
    w.x = f32_to_bf16(u.x * sv.x);
    w.y = f32_to_bf16(u.y * sv.y);
    w.z = f32_to_bf16(u.z * sv.z);
    w.w = f32_to_bf16(u.w * sv.w);
    ((ushort4*)ub)[i] = w;
}

// ---------- reduce split-K partials -> bf16 Y ----------
__global__ void reduce_y(const float* __restrict__ p0, const float* __restrict__ p1,
                         unsigned short* __restrict__ y, int n4) {
    int i = blockIdx.x * blockDim.x + threadIdx.x;
    if (i >= n4) return;
    float4 a = ((const float4*)p0)[i];
    float4 b = ((const float4*)p1)[i];
    ushort4 w;
    w.x = f32_to_bf16(a.x + b.x);
    w.y = f32_to_bf16(a.y + b.y);
    w.z = f32_to_bf16(a.z + b.z);
    w.w = f32_to_bf16(a.w + b.w);
    ((ushort4*)y)[i] = w;
}

// ---------- async global->LDS, 16B per lane ----------
__device__ __forceinline__ void stage16(const unsigned short* g, unsigned short* l) {
    __builtin_amdgcn_global_load_lds(
        (const __attribute__((address_space(1))) uint32_t*)g,
        (__attribute__((address_space(3))) uint32_t*)l, 16, 0, 0);
}

// ============ 256x256 8-phase GEMM template ============
// LDS layout (ushort offsets), per buffer bb (stride 32768 = 64 KiB):
//   A k-half kh: bb*32768 + kh*8192       (16 KiB: 256 rows x 32 cols, chunk-swizzled)
//   B k-half kh: bb*32768 + 16384 + kh*8192
// Chunk swizzle: logical (row, cc) (cc = 16B chunk, 0..3) stored at physical
// chunk row*4 + (cc ^ ((row>>1)&3)).

// stage one k-half-tile of A/B for K-tile t_ into buffer bb (2 loads/thread)
#define STAGE_A(bb, kh, t_) do {                                              \
    const unsigned short* s_ = pAsrc + (t_) * 64 + (kh) * 32;                 \
    unsigned short* d_ = ldsA_dst + (bb) * 32768 + (kh) * 8192;               \
    stage16(s_, d_);                                                          \
    stage16(s_ + (size_t)128 * LD, d_ + 4096);                                \
} while (0)

#define STAGE_B(bb, kh, t_) do {                                              \
    const unsigned short* s_ = pBsrc + (t_) * 64 + (kh) * 32;                 \
    unsigned short* d_ = ldsB_dst + (bb) * 32768 + (kh) * 8192;               \
    stage16(s_, d_);                                                          \
    stage16(s_ + (size_t)128 * LD, d_ + 4096);                                \
} while (0)

#define READ_AF(bb, ks, mh) do {                                              \
    const unsigned short* p_ = lds + (bb) * 32768 + (ks) * 8192 + aoff + (mh) * 2048; \
    af[0] = *(const bf16x8*)(p_);                                             \
    af[1] = *(const bf16x8*)(p_ + 512);                                       \
    af[2] = *(const bf16x8*)(p_ + 1024);                                      \
    af[3] = *(const bf16x8*)(p_ + 1536);                                      \
} while (0)

#define READ_BF(bb, ks) do {                                                  \
    const unsigned short* p_ = lds + (bb) * 32768 + 16384 + (ks) * 8192 + boff; \
    bfr[0] = *(const bf16x8*)(p_);                                            \
    bfr[1] = *(const bf16x8*)(p_ + 512);                                      \
    bfr[2] = *(const bf16x8*)(p_ + 1024);                                     \
    bfr[3] = *(const bf16x8*)(p_ + 1536);                                     \
} while (0)

#define MFMA16(mh) do {                                                       \
    __builtin_amdgcn_s_barrier();                                             \
    __builtin_amdgcn_sched_barrier(0);                                        \
    __builtin_amdgcn_s_setprio(1);                                            \
    _Pragma("unroll") for (int i_ = 0; i_ < 4; ++i_) {                        \
        _Pragma("unroll") for (int n_ = 0; n_ < 4; ++n_) {                    \
            acc[(mh) * 4 + i_][n_] = __builtin_amdgcn_mfma_f32_16x16x32_bf16( \
                af[i_], bfr[n_], acc[(mh) * 4 + i_][n_], 0, 0, 0);            \
        }                                                                     \
    }                                                                         \
    __builtin_amdgcn_s_setprio(0);                                            \
    __builtin_amdgcn_sched_barrier(0);                                        \
} while (0)

#define PHASE_END do {                                                        \
    __builtin_amdgcn_s_barrier();                                             \
    __builtin_amdgcn_sched_barrier(0);                                        \
} while (0)

#define BODY(t_, bb) do {                                                     \
    const int tp1 = (t_) + 1, tp2 = (t_) + 2;                                 \
    bf16x8 af[4], bfr[4];                                                     \
    /* p0: ks=0, mh=0 */                                                      \
    READ_AF(bb, 0, 0); READ_BF(bb, 0);                                        \
    if (tp1 < KTILES) STAGE_A((bb) ^ 1, 1, tp1);                              \
    MFMA16(0); PHASE_END;                                                     \
    /* p1: ks=0, mh=1 */                                                      \
    READ_AF(bb, 0, 1);                                                        \
    if (tp1 < KTILES) STAGE_B((bb) ^ 1, 1, tp1);                              \
    MFMA16(1); PHASE_END;                                                     \
    /* p2: ks=1, mh=0 */                                                      \
    READ_AF(bb, 1, 0); READ_BF(bb, 1);                                        \
    if (tp2 < KTILES) STAGE_A((bb), 0, tp2);                                  \
    MFMA16(0); PHASE_END;                                                     \
    /* p3: ks=1, mh=1 */                                                      \
    READ_AF(bb, 1, 1);                                                        \
    if (tp2 < KTILES) STAGE_B((bb), 0, tp2);                                  \
    MFMA16(1);                                                                \
    if (tp2 < KTILES)      asm volatile("s_waitcnt vmcnt(4)" ::: "memory");   \
    else if (tp1 < KTILES) asm volatile("s_waitcnt vmcnt(0)" ::: "memory");   \
    PHASE_END;                                                                \
} while (0)

template<int KTILES, int LD, int NTX, bool BIAS, int SPLITK>
__global__ __launch_bounds__(512, 2)
void gemm256(const unsigned short* __restrict__ A, const unsigned short* __restrict__ B,
             float* __restrict__ C, const float* __restrict__ bias) {
    static_assert((KTILES % 2) == 0 && KTILES >= 4, "KTILES even >= 4");
    __shared__ unsigned short lds[65536];   // 128 KiB

    const int tid = threadIdx.x;
    const int wv = tid >> 6, lane = tid & 63;
    const int wm = wv >> 2, wn = wv & 3;          // 2 x 4 wave grid
    const int q = lane >> 4, l16 = lane & 15;

    // T1: XCD-aware block swizzle (gridDim.x % 8 == 0 for both instantiations)
    const int cpx = gridDim.x >> 3;
    const int bswz = (blockIdx.x & 7) * cpx + (blockIdx.x >> 3);
    const int tx = bswz % NTX, ty = bswz / NTX;
    const int m0 = ty * 256, n0 = tx * 256;

    const int z = blockIdx.z;
    const unsigned short* Az = A + (size_t)z * SPLITK;
    const unsigned short* Bz = B + (size_t)z * SPLITK;
    float* Cz = C + (size_t)z * 8192 * (NTX * 256);

    // ---- staging: thread tid covers physical chunks {tid, tid+512} of each half-tile.
    // physical chunk pc -> row = pc>>2 (+128 for second load), cc_p = pc&3,
    // logical cc = cc_p ^ ((row>>1)&3)  (inverse-swizzled global source).
    const int rowS = tid >> 2;
    const int ccS  = (tid & 3) ^ ((tid >> 3) & 3);
    const unsigned short* pAsrc = Az + (size_t)(m0 + rowS) * LD + ccS * 8;
    const unsigned short* pBsrc = Bz + (size_t)(n0 + rowS) * LD + ccS * 8;
    unsigned short* ldsA_dst = lds + tid * 8;
    unsigned short* ldsB_dst = lds + 16384 + tid * 8;

    // ---- fragment read offsets (ushort units). row = base16 + l16 => (row>>1)&3 == (l16>>1)&3
    const int xr = (l16 >> 1) & 3;
    const int qx = (q ^ xr) * 8;
    const int aoff = (wm * 128 + l16) * 32 + qx;
    const int boff = (wn * 64 + l16) * 32 + qx;

    f32x4 acc[8][4] = {};

    // ---- prologue: tile0 fully + tile1's k0 halves; wait tile0, leave 4 in flight
    STAGE_A(0, 0, 0); STAGE_B(0, 0, 0);
    STAGE_A(0, 1, 0); STAGE_B(0, 1, 0);
    STAGE_A(1, 0, 1); STAGE_B(1, 0, 1);
    asm volatile("s_waitcnt vmcnt(4)" ::: "memory");
    __builtin_amdgcn_s_barrier();
    __builtin_amdgcn_sched_barrier(0);

    for (int t = 0; t < KTILES; t += 2) {
        BODY(t, 0);
        BODY(t + 1, 1);
    }

    // ---- epilogue
    const int ldc = NTX * 256;
    float bvv[4];
    if (BIAS) {
#pragma unroll
        for (int nf = 0; nf < 4; ++nf) bvv[nf] = bias[n0 + wn * 64 + nf * 16 + l16];
    }
#pragma unroll
    for (int mf = 0; mf < 8; ++mf) {
#pragma unroll
        for (int nf = 0; nf < 4; ++nf) {
            const int col = n0 + wn * 64 + nf * 16 + l16;
            const size_t rb = (size_t)(m0 + wm * 128 + mf * 16 + q * 4);
#pragma unroll
            for (int i = 0; i < 4; ++i) {
                float v = acc[mf][nf][i];
                if (BIAS) v += bvv[nf];
                Cz[(rb + i) * ldc + col] = v;
            }
        }
    }
}

extern "C" void kernel_launch(void* const* d_in, const int* in_sizes, int n_in,
                              void* d_out, int out_size, void* d_ws, size_t ws_size,
                              hipStream_t stream) {
    const float* x    = (const float*)d_in[0];
    const float* u_t  = (const float*)d_in[1];
    const float* u_d  = (const float*)d_in[2];
    const float* s    = (const float*)d_in[3];
    const float* v_t  = (const float*)d_in[4];
    const float* v_d  = (const float*)d_in[5];
    const float* bias = (const float*)d_in[6];
    float* out = (float*)d_out;

    const int M = 8192, IN = 4096, R = 1024, OUT = 4096;

    char* ws = (char*)d_ws;
    float*          Yp = (float*)ws;                                    // 2 x 32 MiB
    unsigned short* xb = (unsigned short*)(ws + (size_t)(64 << 20));    // 64 MiB
    unsigned short* Vb = (unsigned short*)(ws + (size_t)(128 << 20));   //  8 MiB
    unsigned short* Ub = (unsigned short*)(ws + (size_t)(136 << 20));   //  8 MiB
    unsigned short* Yb = (unsigned short*)(ws + (size_t)(144 << 20));   // 16 MiB

    {   // x -> bf16 (streaming)
        int n4 = M * IN / 4;
        cast_f32_bf16<<<(n4 + 255) / 256, 256, 0, stream>>>(x, xb, n4);
    }
    {   // V casts (tiny)
        int n4 = 64 * IN / 4;
        cast_f32_bf16<<<(n4 + 255) / 256, 256, 0, stream>>>(v_t, Vb, n4);
    }
    {
        int n4 = 960 * IN / 4;
        cast_f32_bf16<<<(n4 + 255) / 256, 256, 0, stream>>>(v_d, Vb + 64 * IN, n4);
    }
    {   // U' = U*S -> bf16
        int n4 = OUT * R / 4;
        build_u<<<(n4 + 255) / 256, 256, 0, stream>>>(u_t, u_d, s, Ub, n4);
    }

    // GEMM A: Yp[z] = xb @ Vb^T, split-K=2, 256^2 tiles (32x4 tiles x 2 z = 256 blocks)
    gemm256<32, 4096, 4, false, 2048><<<dim3(128, 1, 2), 512, 0, stream>>>(xb, Vb, Yp, nullptr);
    // reduce partials -> bf16 Y
    {
        int n4 = M * R / 4;
        reduce_y<<<(n4 + 255) / 256, 256, 0, stream>>>(Yp, Yp + (size_t)M * R, Yb, n4);
    }
    // GEMM B: out = Yb @ Ub^T + bias, 256^2 tiles (32x16 = 512 blocks)
    gemm256<16, 1024, 16, true, 0><<<dim3(512, 1, 1), 512, 0, stream>>>(Yb, Ub, out, bias);
}

// Round 2
// 387.425 us; speedup vs baseline: 1.1204x; 1.0684x over previous
//
#include <hip/hip_runtime.h>
#include <cstdint>

// SiVALinear factorized path, R6:
//  - R5 result: T2 swizzle verified (SQ_LDS_BANK_CONFLICT = 0), gemms ~82us each
//    (~835 TF, 33% peak). Remaining stall theory: single vmcnt(4)/K-tile retires
//    half-tiles issued only 3 phases earlier (~latency-exposed at every tile edge).
//  - Change 1 (gemm_b): split the per-tile wait into TWO vmcnt(8) at ends of p1 and
//    p3. FIFO audit: entry invariant = 8 outstanding [A/B(t,k1), A/B(t+1,k0)];
//    p1-end vmcnt(8) retires A/B(t,k1) (5-phase lead), p3-end vmcnt(8) retires
//    A/B(t+1,k0) (5-phase lead). Prologue wait 4 -> 8.
//  - Change 2 (gemm_a): replace split-K=2 + f32 partials + reduce_y with a
//    128x256-tile KTILES=64 kernel: grid 64x4 = 256 blocks = 1/CU, 96 KiB LDS,
//    8 waves (2Mx4N, 64x64/wave), 2 phases/K-tile (16 MFMA + 8 ds_read each),
//    3 stage-ops/phase (A half = 1 op, B half = 2 ops), counted vmcnt(6)/(3)/(0).
//    Writes Yb bf16 directly -> reduce_y and Yp eliminated.
//  - Same chunk swizzle both sides (logical cc -> physical cc^((row>>1)&3)).

typedef __bf16 bf16x8 __attribute__((ext_vector_type(8)));
typedef float f32x4 __attribute__((ext_vector_type(4)));

__device__ __forceinline__ unsigned short f32_to_bf16(float f) {
    union { float f; uint32_t u; } v; v.f = f;
    uint32_t u = v.u;
    u += 0x7FFF + ((u >> 16) & 1);   // RNE
    return (unsigned short)(u >> 16);
}

// ---------- cast fp32 -> bf16, vec4 ----------
__global__ void cast_f32_bf16(const float* __restrict__ src,
                              unsigned short* __restrict__ dst, int n4) {
    int i = blockIdx.x * blockDim.x + threadIdx.x;
    if (i >= n4) return;
    float4 v = ((const float4*)src)[i];
    ushort4 o;
    o.x = f32_to_bf16(v.x); o.y = f32_to_bf16(v.y);
    o.z = f32_to_bf16(v.z); o.w = f32_to_bf16(v.w);
    ((ushort4*)dst)[i] = o;
}

// ---------- build U_cat[o, r] * S[r] -> bf16 [4096 x 1024] row-major ----------
__global__ void build_u(const float* __restrict__ u_t, const float* __restrict__ u_d,
                        const float* __restrict__ s, unsigned short* __restrict__ ub,
                        int n4) {
    int i = blockIdx.x * blockDim.x + threadIdx.x;
    if (i >= n4) return;
    int e = i * 4;
    int o = e >> 10;
    int r = e & 1023;
    float4 u;
    if (r < 64) u = *(const float4*)(u_t + (size_t)o * 64 + r);
    else        u = *(const float4*)(u_d + (size_t)o * 960 + (r - 64));
    float4 sv = *(const float4*)(s + r);
    ushort4 w;
    w.x = f32_to_bf16(u.x * sv.x);
    w.y = f32_to_bf16(u.y * sv.y);
    w.z = f32_to_bf16(u.z * sv.z);
    w.w = f32_to_bf16(u.w * sv.w);
    ((ushort4*)ub)[i] = w;
}

// ---------- async global->LDS, 16B per lane ----------
__device__ __forceinline__ void stage16(const unsigned short* g, unsigned short* l) {
    __builtin_amdgcn_global_load_lds(
        (const __attribute__((address_space(1))) uint32_t*)g,
        (__attribute__((address_space(3))) uint32_t*)l, 16, 0, 0);
}

// ======================================================================
// 256x256 8-phase template (gemm_b)
// ======================================================================
#define STAGE_A(bb, kh, t_) do {                                              \
    const unsigned short* s_ = pAsrc + (t_) * 64 + (kh) * 32;                 \
    unsigned short* d_ = ldsA_dst + (bb) * 32768 + (kh) * 8192;               \
    stage16(s_, d_);                                                          \
    stage16(s_ + (size_t)128 * LD, d_ + 4096);                                \
} while (0)

#define STAGE_B(bb, kh, t_) do {                                              \
    const unsigned short* s_ = pBsrc + (t_) * 64 + (kh) * 32;                 \
    unsigned short* d_ = ldsB_dst + (bb) * 32768 + (kh) * 8192;               \
    stage16(s_, d_);                                                          \
    stage16(s_ + (size_t)128 * LD, d_ + 4096);                                \
} while (0)

#define READ_AF(bb, ks, mh) do {                                              \
    const unsigned short* p_ = lds + (bb) * 32768 + (ks) * 8192 + aoff + (mh) * 2048; \
    af[0] = *(const bf16x8*)(p_);                                             \
    af[1] = *(const bf16x8*)(p_ + 512);                                       \
    af[2] = *(const bf16x8*)(p_ + 1024);                                      \
    af[3] = *(const bf16x8*)(p_ + 1536);                                      \
} while (0)

#define READ_BF(bb, ks) do {                                                  \
    const unsigned short* p_ = lds + (bb) * 32768 + 16384 + (ks) * 8192 + boff; \
    bfr[0] = *(const bf16x8*)(p_);                                            \
    bfr[1] = *(const bf16x8*)(p_ + 512);                                      \
    bfr[2] = *(const bf16x8*)(p_ + 1024);                                     \
    bfr[3] = *(const bf16x8*)(p_ + 1536);                                     \
} while (0)

#define MFMA16(mh) do {                                                       \
    __builtin_amdgcn_s_barrier();                                             \
    __builtin_amdgcn_sched_barrier(0);                                        \
    __builtin_amdgcn_s_setprio(1);                                            \
    _Pragma("unroll") for (int i_ = 0; i_ < 4; ++i_) {                        \
        _Pragma("unroll") for (int n_ = 0; n_ < 4; ++n_) {                    \
            acc[(mh) * 4 + i_][n_] = __builtin_amdgcn_mfma_f32_16x16x32_bf16( \
                af[i_], bfr[n_], acc[(mh) * 4 + i_][n_], 0, 0, 0);            \
        }                                                                     \
    }                                                                         \
    __builtin_amdgcn_s_setprio(0);                                            \
    __builtin_amdgcn_sched_barrier(0);                                        \
} while (0)

#define PHASE_END do {                                                        \
    __builtin_amdgcn_s_barrier();                                             \
    __builtin_amdgcn_sched_barrier(0);                                        \
} while (0)

// Deep-pipeline waits: p1-end and p3-end each retire one half-tile pair with
// a uniform 5-phase issue->wait lead (FIFO-audited, see header comment).
#define BODY(t_, bb) do {                                                     \
    const int tp1 = (t_) + 1, tp2 = (t_) + 2;                                 \
    bf16x8 af[4], bfr[4];                                                     \
    /* p0: ks=0, mh=0 */                                                      \
    READ_AF(bb, 0, 0); READ_BF(bb, 0);                                        \
    if (tp1 < KTILES) STAGE_A((bb) ^ 1, 1, tp1);                              \
    MFMA16(0); PHASE_END;                                                     \
    /* p1: ks=0, mh=1 */                                                      \
    READ_AF(bb, 0, 1);                                                        \
    if (tp1 < KTILES) STAGE_B((bb) ^ 1, 1, tp1);                              \
    MFMA16(1);                                                                \
    if (tp1 < KTILES) asm volatile("s_waitcnt vmcnt(8)" ::: "memory");        \
    else              asm volatile("s_waitcnt vmcnt(0)" ::: "memory");        \
    PHASE_END;                                                                \
    /* p2: ks=1, mh=0 */                                                      \
    READ_AF(bb, 1, 0); READ_BF(bb, 1);                                        \
    if (tp2 < KTILES) STAGE_A((bb), 0, tp2);                                  \
    MFMA16(0); PHASE_END;                                                     \
    /* p3: ks=1, mh=1 */                                                      \
    READ_AF(bb, 1, 1);                                                        \
    if (tp2 < KTILES) STAGE_B((bb), 0, tp2);                                  \
    MFMA16(1);                                                                \
    if (tp2 < KTILES)      asm volatile("s_waitcnt vmcnt(8)" ::: "memory");   \
    else if (tp1 < KTILES) asm volatile("s_waitcnt vmcnt(4)" ::: "memory");   \
    PHASE_END;                                                                \
} while (0)

template<int KTILES, int LD, int NTX, bool BIAS>
__global__ __launch_bounds__(512, 2)
void gemm256(const unsigned short* __restrict__ A, const unsigned short* __restrict__ B,
             float* __restrict__ C, const float* __restrict__ bias) {
    static_assert((KTILES % 2) == 0 && KTILES >= 4, "KTILES even >= 4");
    __shared__ unsigned short lds[65536];   // 128 KiB

    const int tid = threadIdx.x;
    const int wv = tid >> 6, lane = tid & 63;
    const int wm = wv >> 2, wn = wv & 3;          // 2 x 4 wave grid
    const int q = lane >> 4, l16 = lane & 15;

    const int cpx = gridDim.x >> 3;
    const int bswz = (blockIdx.x & 7) * cpx + (blockIdx.x >> 3);
    const int tx = bswz % NTX, ty = bswz / NTX;
    const int m0 = ty * 256, n0 = tx * 256;

    const int rowS = tid >> 2;
    const int ccS  = (tid & 3) ^ ((tid >> 3) & 3);
    const unsigned short* pAsrc = A + (size_t)(m0 + rowS) * LD + ccS * 8;
    const unsigned short* pBsrc = B + (size_t)(n0 + rowS) * LD + ccS * 8;
    unsigned short* ldsA_dst = lds + tid * 8;
    unsigned short* ldsB_dst = lds + 16384 + tid * 8;

    const int xr = (l16 >> 1) & 3;
    const int qx = (q ^ xr) * 8;
    const int aoff = (wm * 128 + l16) * 32 + qx;
    const int boff = (wn * 64 + l16) * 32 + qx;

    f32x4 acc[8][4] = {};

    // prologue: tile0 (k0,k1) + tile1 k0 issued (12 loads); wait 8 -> tile0 k0 landed
    STAGE_A(0, 0, 0); STAGE_B(0, 0, 0);
    STAGE_A(0, 1, 0); STAGE_B(0, 1, 0);
    STAGE_A(1, 0, 1); STAGE_B(1, 0, 1);
    asm volatile("s_waitcnt vmcnt(8)" ::: "memory");
    __builtin_amdgcn_s_barrier();
    __builtin_amdgcn_sched_barrier(0);

    for (int t = 0; t < KTILES; t += 2) {
        BODY(t, 0);
        BODY(t + 1, 1);
    }

    const int ldc = NTX * 256;
    float bvv[4];
    if (BIAS) {
#pragma unroll
        for (int nf = 0; nf < 4; ++nf) bvv[nf] = bias[n0 + wn * 64 + nf * 16 + l16];
    }
#pragma unroll
    for (int mf = 0; mf < 8; ++mf) {
#pragma unroll
        for (int nf = 0; nf < 4; ++nf) {
            const int col = n0 + wn * 64 + nf * 16 + l16;
            const size_t rb = (size_t)(m0 + wm * 128 + mf * 16 + q * 4);
#pragma unroll
            for (int i = 0; i < 4; ++i) {
                float v = acc[mf][nf][i];
                if (BIAS) v += bvv[nf];
                C[(rb + i) * ldc + col] = v;
            }
        }
    }
}

// ======================================================================
// 128x256-tile KTILES=64 kernel (gemm_a): Yb[8192,1024](bf16) = xb @ Vb^T
// LDS per buffer bb (stride 24576 ushorts = 48 KiB):
//   A kh: bb*24576 + kh*4096   (128 rows x 32 k)    staging: 1 op
//   B kh: bb*24576 + 8192 + kh*8192 (256 x 32)      staging: 2 ops
// ======================================================================
#define ST2_A(bb, kh, t_)                                                     \
    stage16(pAsrc + (t_) * 64 + (kh) * 32, lds + (bb) * 24576 + (kh) * 4096 + tid * 8)

#define ST2_B(bb, kh, t_) do {                                                \
    const unsigned short* s_ = pBsrc + (t_) * 64 + (kh) * 32;                 \
    unsigned short* d_ = lds + (bb) * 24576 + 8192 + (kh) * 8192 + tid * 8;   \
    stage16(s_, d_);                                                          \
    stage16(s_ + (size_t)128 * 4096, d_ + 4096);                              \
} while (0)

#define RD2_A(bb, ks) do {                                                    \
    const unsigned short* p_ = lds + (bb) * 24576 + (ks) * 4096 + aoff;       \
    af[0] = *(const bf16x8*)(p_);                                             \
    af[1] = *(const bf16x8*)(p_ + 512);                                       \
    af[2] = *(const bf16x8*)(p_ + 1024);                                      \
    af[3] = *(const bf16x8*)(p_ + 1536);                                      \
} while (0)

#define RD2_B(bb, ks) do {                                                    \
    const unsigned short* p_ = lds + (bb) * 24576 + 8192 + (ks) * 8192 + boff; \
    bfr[0] = *(const bf16x8*)(p_);                                            \
    bfr[1] = *(const bf16x8*)(p_ + 512);                                      \
    bfr[2] = *(const bf16x8*)(p_ + 1024);                                     \
    bfr[3] = *(const bf16x8*)(p_ + 1536);                                     \
} while (0)

#define MM16 do {                                                             \
    __builtin_amdgcn_s_barrier();                                             \
    __builtin_amdgcn_sched_barrier(0);                                        \
    __builtin_amdgcn_s_setprio(1);                                            \
    _Pragma("unroll") for (int i_ = 0; i_ < 4; ++i_) {                        \
        _Pragma("unroll") for (int n_ = 0; n_ < 4; ++n_) {                    \
            acc[i_][n_] = __builtin_amdgcn_mfma_f32_16x16x32_bf16(            \
                af[i_], bfr[n_], acc[i_][n_], 0, 0, 0);                       \
        }                                                                     \
    }                                                                         \
    __builtin_amdgcn_s_setprio(0);                                            \
    __builtin_amdgcn_sched_barrier(0);                                        \
} while (0)

// Hazards (tile t -> buffer bb=t&1, tile t+2 -> bb):
//  pA stages (bb^1,k1,t+1): region last read BODY(t-1) pB, >=1 barrier ago. OK
//  pB stages (bb,k0,t+2):   region last read this body's pA.              OK
// FIFO waits (ops: A-half=1, B-half=2, 3/phase):
//  entry invariant 6 outstanding [A/B(t,k1), A/B(t+1,k0)];
//  pA-end vmcnt(6) retires A/B(t,k1) (needed pB, 2-phase lead);
//  pB-end vmcnt(6) retires A/B(t+1,k0) (needed next pA, 3-phase lead).
#define BODY2(t_, bb) do {                                                    \
    const int tp1 = (t_) + 1, tp2 = (t_) + 2;                                 \
    bf16x8 af[4], bfr[4];                                                     \
    /* pA: ks=0 */                                                            \
    RD2_A(bb, 0); RD2_B(bb, 0);                                               \
    if (tp1 < 64) { ST2_A((bb) ^ 1, 1, tp1); ST2_B((bb) ^ 1, 1, tp1); }       \
    MM16;                                                                     \
    if (tp1 < 64) asm volatile("s_waitcnt vmcnt(6)" ::: "memory");            \
    else          asm volatile("s_waitcnt vmcnt(0)" ::: "memory");            \
    PHASE_END;                                                                \
    /* pB: ks=1 */                                                            \
    RD2_A(bb, 1); RD2_B(bb, 1);                                               \
    if (tp2 < 64) { ST2_A((bb), 0, tp2); ST2_B((bb), 0, tp2); }               \
    MM16;                                                                     \
    if (tp2 < 64)      asm volatile("s_waitcnt vmcnt(6)" ::: "memory");       \
    else if (tp1 < 64) asm volatile("s_waitcnt vmcnt(3)" ::: "memory");       \
    PHASE_END;                                                                \
} while (0)

__global__ __launch_bounds__(512, 2)
void gemm_a128(const unsigned short* __restrict__ A, const unsigned short* __restrict__ B,
               unsigned short* __restrict__ Y) {
    __shared__ unsigned short lds[49152];   // 96 KiB

    const int tid = threadIdx.x;
    const int wv = tid >> 6, lane = tid & 63;
    const int wm = wv >> 2, wn = wv & 3;          // 2 x 4 wave grid, 64x64 per wave
    const int q = lane >> 4, l16 = lane & 15;

    // XCD swizzle: 256 blocks, 32 per XCD chunk
    const int bswz = (blockIdx.x & 7) * 32 + (blockIdx.x >> 3);
    const int tx = bswz & 3, ty = bswz >> 2;
    const int m0 = ty * 128, n0 = tx * 256;

    const int rowS = tid >> 2;
    const int ccS  = (tid & 3) ^ ((tid >> 3) & 3);
    const unsigned short* pAsrc = A + (size_t)(m0 + rowS) * 4096 + ccS * 8;
    const unsigned short* pBsrc = B + (size_t)(n0 + rowS) * 4096 + ccS * 8;

    const int xr = (l16 >> 1) & 3;
    const int qx = (q ^ xr) * 8;
    const int aoff = (wm * 64 + l16) * 32 + qx;
    const int boff = (wn * 64 + l16) * 32 + qx;

    f32x4 acc[4][4] = {};

    // prologue: tile0 k0,k1 + tile1 k0 (9 ops); wait 6 -> tile0 k0 landed
    ST2_A(0, 0, 0); ST2_B(0, 0, 0);
    ST2_A(0, 1, 0); ST2_B(0, 1, 0);
    ST2_A(1, 0, 1); ST2_B(1, 0, 1);
    asm volatile("s_waitcnt vmcnt(6)" ::: "memory");
    __builtin_amdgcn_s_barrier();
    __builtin_amdgcn_sched_barrier(0);

    for (int t = 0; t < 64; t += 2) {
        BODY2(t, 0);
        BODY2(t + 1, 1);
    }

    // epilogue: bf16 store
#pragma unroll
    for (int mf = 0; mf < 4; ++mf) {
#pragma unroll
        for (int nf = 0; nf < 4; ++nf) {
            const int col = n0 + wn * 64 + nf * 16 + l16;
            const size_t rb = (size_t)(m0 + wm * 64 + mf * 16 + q * 4);
#pragma unroll
            for (int i = 0; i < 4; ++i)
                Y[(rb + i) * 1024 + col] = f32_to_bf16(acc[mf][nf][i]);
        }
    }
}

extern "C" void kernel_launch(void* const* d_in, const int* in_sizes, int n_in,
                              void* d_out, int out_size, void* d_ws, size_t ws_size,
                              hipStream_t stream) {
    const float* x    = (const float*)d_in[0];
    const float* u_t  = (const float*)d_in[1];
    const float* u_d  = (const float*)d_in[2];
    const float* s    = (const float*)d_in[3];
    const float* v_t  = (const float*)d_in[4];
    const float* v_d  = (const float*)d_in[5];
    const float* bias = (const float*)d_in[6];
    float* out = (float*)d_out;

    const int M = 8192, IN = 4096, R = 1024, OUT = 4096;

    char* ws = (char*)d_ws;
    unsigned short* xb = (unsigned short*)ws;                           // 64 MiB
    unsigned short* Vb = (unsigned short*)(ws + (size_t)(64 << 20));    //  8 MiB
    unsigned short* Ub = (unsigned short*)(ws + (size_t)(72 << 20));    //  8 MiB
    unsigned short* Yb = (unsigned short*)(ws + (size_t)(80 << 20));    // 16 MiB

    {   // x -> bf16 (streaming, BW-roofline already)
        int n4 = M * IN / 4;
        cast_f32_bf16<<<(n4 + 255) / 256, 256, 0, stream>>>(x, xb, n4);
    }
    {   // V casts (tiny)
        int n4 = 64 * IN / 4;
        cast_f32_bf16<<<(n4 + 255) / 256, 256, 0, stream>>>(v_t, Vb, n4);
    }
    {
        int n4 = 960 * IN / 4;
        cast_f32_bf16<<<(n4 + 255) / 256, 256, 0, stream>>>(v_d, Vb + 64 * IN, n4);
    }
    {   // U' = U*S -> bf16
        int n4 = OUT * R / 4;
        build_u<<<(n4 + 255) / 256, 256, 0, stream>>>(u_t, u_d, s, Ub, n4);
    }

    // GEMM A: Yb = xb @ Vb^T, 128x256 tiles, K=4096 deep, direct bf16 out
    gemm_a128<<<dim3(256, 1, 1), 512, 0, stream>>>(xb, Vb, Yb);
    // GEMM B: out = Yb @ Ub^T + bias, 256^2 tiles (32x16 = 512 blocks)
    gemm256<16, 1024, 16, true><<<dim3(512, 1, 1), 512, 0, stream>>>(Yb, Ub, out, bias);
}